// Round 3
// baseline (3728.700 us; speedup 1.0000x reference)
//
#include <hip/hip_runtime.h>
#include <hip/hip_bf16.h>

#define TT 20
#define BB 64
#define HH 512
#define EE 512
#define VV 32000
#define NBLK 32

typedef __bf16 bf16x8 __attribute__((ext_vector_type(8)));
typedef float f32x4 __attribute__((ext_vector_type(4)));
typedef unsigned long long u64;

template <int L> struct IC { static constexpr int value = L; };

__device__ __forceinline__ void gload_lds16(const __hip_bfloat16* g, __hip_bfloat16* l) {
    __builtin_amdgcn_global_load_lds((const __attribute__((address_space(1))) void*)g,
                                     (__attribute__((address_space(3))) void*)l, 16, 0, 0);
}

__device__ __forceinline__ float sigmf(float x) { return 1.f / (1.f + __expf(-x)); }

// coherent (L2-bypass, no-invalidate) 16B load as 2x relaxed agent-scope 8B atomics
__device__ __forceinline__ bf16x8 cload8(const __hip_bfloat16* p) {
    union { u64 q[2]; bf16x8 v; } u;
    u.q[0] = __hip_atomic_load((const u64*)p, __ATOMIC_RELAXED, __HIP_MEMORY_SCOPE_AGENT);
    u.q[1] = __hip_atomic_load((const u64*)p + 1, __ATOMIC_RELAXED, __HIP_MEMORY_SCOPE_AGENT);
    return u.v;
}

__device__ __forceinline__ void cstore4(__hip_bfloat16* p, u64 v) {
    __hip_atomic_store((u64*)p, v, __ATOMIC_RELAXED, __HIP_MEMORY_SCOPE_AGENT);
}

// ---------------- elementwise helpers ----------------

__global__ __launch_bounds__(256) void f2bf_kernel(const float* __restrict__ in,
                                                   __hip_bfloat16* __restrict__ out, int n) {
    int i = blockIdx.x * 256 + threadIdx.x;
    if (i < n) out[i] = __float2bfloat16(in[i]);
}

__global__ __launch_bounds__(256) void gather_emb_kernel(const float* __restrict__ tab,
                                                         const int* __restrict__ cap,
                                                         __hip_bfloat16* __restrict__ out) {
    int i = blockIdx.x * 256 + threadIdx.x;  // T*B*E total
    int e = i & (EE - 1);
    int tb = i >> 9;
    int t = tb >> 6;
    int b = tb & 63;
    int tok = cap[b * TT + t];
    out[i] = __float2bfloat16(tab[(size_t)tok * EE + e]);
}

// zero both h ping-pong buffers + barrier counter
__global__ __launch_bounds__(256) void init_kernel(__hip_bfloat16* __restrict__ hb,
                                                   int* __restrict__ bar) {
    int i = blockIdx.x * 256 + threadIdx.x;  // 2*3*64*512 threads
    hb[i] = __float2bfloat16(0.f);
    if (i < 64) bar[i] = 0;
}

// ---------------- gemm128: C[M,N] = A[M,K] @ B[N,K]^T (+bias), fp32 out ----------------

__global__ __launch_bounds__(256) void gemm128_kernel(
    const __hip_bfloat16* __restrict__ A,
    const __hip_bfloat16* __restrict__ Bm,
    const float* __restrict__ bias,
    float* __restrict__ C,
    int K, int N)
{
    __shared__ __align__(16) __hip_bfloat16 As[128 * 32];
    __shared__ __align__(16) __hip_bfloat16 Bs[128 * 32];

    int m0 = blockIdx.x * 128, n0 = blockIdx.y * 128;
    int tid = threadIdx.x;
    int wave = tid >> 6, lane = tid & 63;
    int wm = wave & 1, wn = wave >> 1;
    int row16 = lane & 15, quad = lane >> 4;

    int r0 = tid >> 2, cc = (tid & 3) * 8;
    int r1 = 64 + r0;
    const __hip_bfloat16* gA0 = A  + (size_t)(m0 + r0) * K + cc;
    const __hip_bfloat16* gA1 = A  + (size_t)(m0 + r1) * K + cc;
    const __hip_bfloat16* gB0 = Bm + (size_t)(n0 + r0) * K + cc;
    const __hip_bfloat16* gB1 = Bm + (size_t)(n0 + r1) * K + cc;
    __hip_bfloat16* lA0 = As + (size_t)(wave * 64) * 8;
    __hip_bfloat16* lA1 = As + (size_t)(256 + wave * 64) * 8;
    __hip_bfloat16* lB0 = Bs + (size_t)(wave * 64) * 8;
    __hip_bfloat16* lB1 = Bs + (size_t)(256 + wave * 64) * 8;

    const __hip_bfloat16* ra = As + (size_t)(wm * 64 + row16) * 32 + quad * 8;
    const __hip_bfloat16* rb = Bs + (size_t)(wn * 64 + row16) * 32 + quad * 8;

    f32x4 acc[4][4] = {};

    for (int k = 0; k < K; k += 32) {
        gload_lds16(gA0 + k, lA0);
        gload_lds16(gA1 + k, lA1);
        gload_lds16(gB0 + k, lB0);
        gload_lds16(gB1 + k, lB1);
        __syncthreads();
        bf16x8 af[4], bfr[4];
#pragma unroll
        for (int mt = 0; mt < 4; ++mt)
            af[mt] = *reinterpret_cast<const bf16x8*>(ra + mt * 16 * 32);
#pragma unroll
        for (int nt = 0; nt < 4; ++nt)
            bfr[nt] = *reinterpret_cast<const bf16x8*>(rb + nt * 16 * 32);
#pragma unroll
        for (int mt = 0; mt < 4; ++mt)
#pragma unroll
            for (int nt = 0; nt < 4; ++nt)
                acc[mt][nt] = __builtin_amdgcn_mfma_f32_16x16x32_bf16(af[mt], bfr[nt], acc[mt][nt], 0, 0, 0);
        __syncthreads();
    }

#pragma unroll
    for (int mt = 0; mt < 4; ++mt)
#pragma unroll
        for (int nt = 0; nt < 4; ++nt) {
            int col = n0 + wn * 64 + nt * 16 + row16;
            float bv = bias ? bias[col] : 0.f;
#pragma unroll
            for (int r = 0; r < 4; ++r) {
                int row = m0 + wm * 64 + mt * 16 + quad * 4 + r;
                C[(size_t)row * N + col] = acc[mt][nt][r] + bv;
            }
        }
}

// ---------------- persistent recurrence kernel ----------------
// 32 blocks x 512 thr. Block owns 16-col h slice (GRU) and 2 batches (attn).
// Barrier: monotonic relaxed-atomic counter (NO acquire/release -> no L2 inv/wb:
// weights/KV/GI0 stay L2-resident the whole kernel). Cross-block h-state goes
// through relaxed agent-scope atomics (sc0sc1: bypass L2, read/write L3).
// fp32 h lives in registers (thread-owned). 3 grid barriers per timestep.

__global__ __launch_bounds__(512) void recurrence_kernel(
    const float* __restrict__ GI0,            // [1280][1536] = xemb @ Wih0^T
    const __hip_bfloat16* __restrict__ wih,   // [3][1536][512]
    const __hip_bfloat16* __restrict__ whh,   // [3][1536][512]
    const float* __restrict__ bih,            // [3][1536]
    const float* __restrict__ bhh,
    const __hip_bfloat16* __restrict__ wq,    // [512][512] (in_proj rows 0..511)
    const float* __restrict__ bq,
    const __hip_bfloat16* __restrict__ wo,    // [512][512]
    const float* __restrict__ bo,
    const float* __restrict__ KV,             // [4096][1024] fp32 (K | V)
    __hip_bfloat16* __restrict__ hb,          // [2][3][64][512] bf16 ping-pong
    __hip_bfloat16* __restrict__ AO,          // [1280][512] (row = b*T + t)
    int* __restrict__ bar)
{
    __shared__ float smem[24 * 544];  // parts[24][32][17] padded; attn aliases low 12KB

    const int tid = threadIdx.x;
    const int w = tid >> 6, lane = tid & 63;
    const int row16 = lane & 15, quad = lane >> 4;
    const int blk = blockIdx.x;
    const int c0 = blk * 16;
    const size_t HS = (size_t)64 * 512;

    f32x4 h0r = {0.f, 0.f, 0.f, 0.f}, h1r = h0r, h2r = h0r;

    int lgen = 0;
    auto gridbar = [&]() {
        asm volatile("s_waitcnt vmcnt(0)" ::: "memory");
        __syncthreads();
        if (tid == 0) {
            lgen++;
            __hip_atomic_fetch_add(&bar[0], 1, __ATOMIC_RELAXED, __HIP_MEMORY_SCOPE_AGENT);
            while (__hip_atomic_load(&bar[0], __ATOMIC_RELAXED, __HIP_MEMORY_SCOPE_AGENT) < NBLK * lgen)
                __builtin_amdgcn_s_sleep(1);
        }
        __syncthreads();
    };

#define PART(s, r, c) smem[(s) * 544 + (r) * 17 + (c)]

    auto gru_stage = [&](auto LC, int t, int cur) {
        constexpr int l = decltype(LC)::value;
        const int nxt = cur ^ 1;
        const __hip_bfloat16* hown = hb + (size_t)(cur * 3 + l) * HS;
        const __hip_bfloat16* xin  = l ? hb + (size_t)(nxt * 3 + (l - 1)) * HS : hown;
        const __hip_bfloat16* Wihl = wih + (size_t)l * 1536 * 512;
        const __hip_bfloat16* Whhl = whh + (size_t)l * 1536 * 512;

        // wave job: l==0: (rh, kseg/4) over Whh only; l>0: (src, rh, kseg/2)
        int src, rh, kseg, koff;
        constexpr int nk = l ? 8 : 4;
        if (l) { src = w >> 2; rh = (w >> 1) & 1; kseg = w & 1; koff = kseg * 256; }
        else   { src = 1;      rh = w >> 2;       kseg = w & 3; koff = kseg * 128; }

        const __hip_bfloat16* Ab = (src ? hown : xin) + (size_t)(rh * 32) * 512 + koff;
        const __hip_bfloat16* Wm = src ? Whhl : Wihl;
        const __hip_bfloat16* pa0 = Ab + (size_t)row16 * 512 + quad * 8;
        const __hip_bfloat16* pa1 = pa0 + (size_t)16 * 512;
        const __hip_bfloat16* pw  = Wm + (size_t)(c0 + row16) * 512 + quad * 8 + koff;

        f32x4 acc[3][2] = {};
#pragma unroll
        for (int kg = 0; kg < nk; kg += 2) {
            int kb = kg * 32;
            bf16x8 a00 = cload8(pa0 + kb), a01 = cload8(pa0 + kb + 32);
            bf16x8 a10 = cload8(pa1 + kb), a11 = cload8(pa1 + kb + 32);
#pragma unroll
            for (int g = 0; g < 3; ++g) {
                bf16x8 w0 = *reinterpret_cast<const bf16x8*>(pw + (size_t)g * 262144 + kb);
                bf16x8 w1 = *reinterpret_cast<const bf16x8*>(pw + (size_t)g * 262144 + kb + 32);
                acc[g][0] = __builtin_amdgcn_mfma_f32_16x16x32_bf16(a00, w0, acc[g][0], 0, 0, 0);
                acc[g][1] = __builtin_amdgcn_mfma_f32_16x16x32_bf16(a10, w0, acc[g][1], 0, 0, 0);
                acc[g][0] = __builtin_amdgcn_mfma_f32_16x16x32_bf16(a01, w1, acc[g][0], 0, 0, 0);
                acc[g][1] = __builtin_amdgcn_mfma_f32_16x16x32_bf16(a11, w1, acc[g][1], 0, 0, 0);
            }
        }
#pragma unroll
        for (int g = 0; g < 3; ++g) {
            int slot = l ? (g * 8 + src * 4 + rh * 2 + kseg) : (g * 8 + rh * 4 + kseg);
#pragma unroll
            for (int mf = 0; mf < 2; ++mf)
#pragma unroll
                for (int r = 0; r < 4; ++r)
                    PART(slot, mf * 16 + quad * 4 + r, row16) = acc[g][mf][r];
        }
        __syncthreads();

        if (tid < 256) {
            int row = tid >> 2, cg = tid & 3;
            int rh2 = row >> 5, lr = row & 31;
            const float* bihl = bih + l * 1536;
            const float* bhhl = bhh + l * 1536;
            f32x4& hr = (l == 0) ? h0r : (l == 1) ? h1r : h2r;
            f32x4 gi4[3];
            if (!l) {
                const float* gp = GI0 + (size_t)(t * 64 + row) * 1536 + c0 + cg * 4;
#pragma unroll
                for (int g = 0; g < 3; ++g)
                    gi4[g] = *reinterpret_cast<const f32x4*>(gp + g * 512);
            }
            union { unsigned short us[4]; u64 u; } pk;
#pragma unroll
            for (int cc = 0; cc < 4; ++cc) {
                int col16 = cg * 4 + cc, col = c0 + col16;
                float gi[3], gh[3];
#pragma unroll
                for (int g = 0; g < 3; ++g) {
                    if (l) {
                        gi[g] = PART(g * 8 + rh2 * 2, lr, col16) + PART(g * 8 + rh2 * 2 + 1, lr, col16);
                        gh[g] = PART(g * 8 + 4 + rh2 * 2, lr, col16) + PART(g * 8 + 4 + rh2 * 2 + 1, lr, col16);
                    } else {
                        gh[g] = PART(g * 8 + rh2 * 4, lr, col16) + PART(g * 8 + rh2 * 4 + 1, lr, col16) +
                                PART(g * 8 + rh2 * 4 + 2, lr, col16) + PART(g * 8 + rh2 * 4 + 3, lr, col16);
                        gi[g] = gi4[g][cc];
                    }
                }
                float rr = sigmf(gi[0] + gh[0] + bihl[col] + bhhl[col]);
                float zz = sigmf(gi[1] + gh[1] + bihl[512 + col] + bhhl[512 + col]);
                float nn = tanhf(gi[2] + bihl[1024 + col] + rr * (gh[2] + bhhl[1024 + col]));
                float hnew = (1.f - zz) * nn + zz * hr[cc];
                hr[cc] = hnew;
                __hip_bfloat16 hv = __float2bfloat16(hnew);
                pk.us[cc] = *reinterpret_cast<unsigned short*>(&hv);
            }
            cstore4(hb + (size_t)(nxt * 3 + l) * HS + (size_t)row * 512 + c0 + cg * 4, pk.u);
        }
    };

    // fused q-proj + attention + out-proj; block owns batches 2*blk, 2*blk+1
    auto attn_stage = [&](int t, int nxt) {
        float* h2f = smem;          // [2][512]
        float* qs  = smem + 1024;   // [2][512]
        float* cs  = smem + 2048;   // [2][512]
        const int b0 = blk * 2;
        const __hip_bfloat16* h2b = hb + (size_t)(nxt * 3 + 2) * HS;

        if (tid < 128) {
            int bl = tid >> 6, k8 = tid & 63;
            bf16x8 hv = cload8(h2b + (size_t)(b0 + bl) * 512 + k8 * 8);
            float* d = h2f + bl * 512 + k8 * 8;
#pragma unroll
            for (int e = 0; e < 8; ++e) d[e] = (float)hv[e];
        }
        __syncthreads();

        // q[bl][tid] = bq + h2 . wq_row(tid)
#pragma unroll 1
        for (int bl = 0; bl < 2; ++bl) {
            float s = bq[tid];
            const __hip_bfloat16* wrow = wq + (size_t)tid * 512;
            const float* hs = h2f + bl * 512;
#pragma unroll 4
            for (int k8 = 0; k8 < 64; ++k8) {
                bf16x8 wv = *reinterpret_cast<const bf16x8*>(wrow + k8 * 8);
#pragma unroll
                for (int e = 0; e < 8; ++e) s += hs[k8 * 8 + e] * (float)wv[e];
            }
            qs[bl * 512 + tid] = s;
        }
        __syncthreads();

        // per (bl, head=w): softmax attention; lane = kv pos, then lane = dim
#pragma unroll 1
        for (int bl = 0; bl < 2; ++bl) {
            int b = b0 + bl;
            const float* qh = qs + bl * 512 + w * 64;
            const float* kr = KV + (size_t)(b * 64 + lane) * 1024 + w * 64;
            float sc = 0.f;
#pragma unroll
            for (int d4 = 0; d4 < 16; ++d4) {
                f32x4 kv4 = *reinterpret_cast<const f32x4*>(kr + d4 * 4);
                f32x4 qv4 = *reinterpret_cast<const f32x4*>(qh + d4 * 4);
                sc += qv4[0] * kv4[0] + qv4[1] * kv4[1] + qv4[2] * kv4[2] + qv4[3] * kv4[3];
            }
            sc *= 0.125f;  // 1/sqrt(64)
            float m = sc;
            for (int off = 32; off; off >>= 1) m = fmaxf(m, __shfl_xor(m, off, 64));
            float e = __expf(sc - m);
            float s = e;
            for (int off = 32; off; off >>= 1) s += __shfl_xor(s, off, 64);
            float p = e / s;
            const float* vb = KV + (size_t)(b * 64) * 1024 + 512 + w * 64 + lane;
            float acc = 0.f;
#pragma unroll
            for (int si = 0; si < 64; ++si)
                acc += __shfl(p, si, 64) * vb[(size_t)si * 1024];
            cs[bl * 512 + w * 64 + lane] = acc;
        }
        __syncthreads();

        // AO[(b*T+t)][tid] = bo + ctx . wo_row(tid)
#pragma unroll 1
        for (int bl = 0; bl < 2; ++bl) {
            float s = bo[tid];
            const __hip_bfloat16* wrow = wo + (size_t)tid * 512;
            const float* csr = cs + bl * 512;
#pragma unroll 4
            for (int k8 = 0; k8 < 64; ++k8) {
                bf16x8 wv = *reinterpret_cast<const bf16x8*>(wrow + k8 * 8);
#pragma unroll
                for (int e = 0; e < 8; ++e) s += csr[k8 * 8 + e] * (float)wv[e];
            }
            AO[((size_t)(b0 + bl) * TT + t) * 512 + tid] = __float2bfloat16(s);
        }
        __syncthreads();  // protect smem before next step's store_parts
    };

#pragma unroll 1
    for (int t = 0; t < TT; ++t) {
        int cur = t & 1, nxt = cur ^ 1;
        gru_stage(IC<0>{}, t, cur); gridbar();
        gru_stage(IC<1>{}, t, cur); gridbar();
        gru_stage(IC<2>{}, t, cur); gridbar();
        attn_stage(t, nxt);
        // no trailing grid barrier: next step's l0/l1 touch only layer-0/1 buffers;
        // hb[*][2] WAR is >=4 barriers away; AO/GI0/KV have no in-kernel readers/writers.
    }
#undef PART
}

// ---------------- host ----------------

extern "C" void kernel_launch(void* const* d_in, const int* in_sizes, int n_in,
                              void* d_out, int out_size, void* d_ws, size_t ws_size,
                              hipStream_t stream) {
    const float* enc        = (const float*)d_in[0];
    const int*   cap        = (const int*)d_in[1];
    const float* emb_tab    = (const float*)d_in[2];
    const float* w_ih       = (const float*)d_in[3];
    const float* w_hh       = (const float*)d_in[4];
    const float* b_ih       = (const float*)d_in[5];
    const float* b_hh       = (const float*)d_in[6];
    const float* in_proj_w  = (const float*)d_in[7];
    const float* in_proj_b  = (const float*)d_in[8];
    const float* out_proj_w = (const float*)d_in[9];
    const float* out_proj_b = (const float*)d_in[10];
    const float* fc_w       = (const float*)d_in[11];
    const float* fc_b       = (const float*)d_in[12];
    float* out = (float*)d_out;

    char* p = (char*)d_ws;
    auto alloc = [&](size_t bytes) {
        char* r = p;
        p += (bytes + 255) & ~(size_t)255;
        return r;
    };
    __hip_bfloat16* fcw_bf  = (__hip_bfloat16*)alloc((size_t)VV * HH * 2);
    __hip_bfloat16* enc_bf  = (__hip_bfloat16*)alloc((size_t)BB * 64 * HH * 2);
    __hip_bfloat16* inp_bf  = (__hip_bfloat16*)alloc((size_t)1536 * 512 * 2);
    __hip_bfloat16* wih_bf  = (__hip_bfloat16*)alloc((size_t)3 * 1536 * 512 * 2);
    __hip_bfloat16* whh_bf  = (__hip_bfloat16*)alloc((size_t)3 * 1536 * 512 * 2);
    __hip_bfloat16* wo_bf   = (__hip_bfloat16*)alloc((size_t)512 * 512 * 2);
    __hip_bfloat16* xemb_bf = (__hip_bfloat16*)alloc((size_t)TT * BB * EE * 2);
    float* KV   = (float*)alloc((size_t)4096 * 1024 * 4);
    float* GI0  = (float*)alloc((size_t)1280 * 1536 * 4);
    __hip_bfloat16* hb = (__hip_bfloat16*)alloc((size_t)2 * 3 * 64 * 512 * 2);
    __hip_bfloat16* AO = (__hip_bfloat16*)alloc((size_t)1280 * 512 * 2);
    int* bar = (int*)alloc(256);

    auto cvt = [&](const float* src, __hip_bfloat16* dst, int n) {
        f2bf_kernel<<<(n + 255) / 256, 256, 0, stream>>>(src, dst, n);
    };
    cvt(fc_w, fcw_bf, VV * HH);
    cvt(enc, enc_bf, BB * 64 * HH);
    cvt(in_proj_w, inp_bf, 1536 * 512);
    cvt(w_ih, wih_bf, 3 * 1536 * 512);
    cvt(w_hh, whh_bf, 3 * 1536 * 512);
    cvt(out_proj_w, wo_bf, 512 * 512);
    gather_emb_kernel<<<(TT * BB * EE) / 256, 256, 0, stream>>>(emb_tab, cap, xemb_bf);
    init_kernel<<<(2 * 3 * 64 * 512) / 256, 256, 0, stream>>>(hb, bar);

    // KV = enc @ [Wk;Wv]^T + [bk;bv]   (4096 x 1024, K=512)
    gemm128_kernel<<<dim3(32, 8), 256, 0, stream>>>(
        enc_bf, inp_bf + 512 * 512, in_proj_b + 512, KV, 512, 1024);

    // GI0 = xemb @ Wih0^T   (1280 x 1536, no bias)
    gemm128_kernel<<<dim3(10, 12), 256, 0, stream>>>(
        xemb_bf, wih_bf, nullptr, GI0, 512, 1536);

    // whole recurrence in one persistent kernel
    recurrence_kernel<<<NBLK, 512, 0, stream>>>(
        GI0, wih_bf, whh_bf, b_ih, b_hh,
        inp_bf, in_proj_b, wo_bf, out_proj_b,
        KV, hb, AO, bar);

    // logits = AO @ fc_w^T + fc_b   (1280 x 32000) -> d_out (B,T,V)
    gemm128_kernel<<<dim3(10, 250), 256, 0, stream>>>(
        AO, fcw_bf, fc_b, out, 512, VV);
}

// Round 4
// 3434.284 us; speedup vs baseline: 1.0857x; 1.0857x over previous
//
#include <hip/hip_runtime.h>
#include <hip/hip_bf16.h>

#define TT 20
#define BB 64
#define HH 512
#define EE 512
#define VV 32000
#define NBLK 32

typedef __bf16 bf16x8 __attribute__((ext_vector_type(8)));
typedef float f32x4 __attribute__((ext_vector_type(4)));
typedef unsigned long long u64;

template <int L> struct IC { static constexpr int value = L; };

__device__ __forceinline__ void gload_lds16(const __hip_bfloat16* g, __hip_bfloat16* l) {
    __builtin_amdgcn_global_load_lds((const __attribute__((address_space(1))) void*)g,
                                     (__attribute__((address_space(3))) void*)l, 16, 0, 0);
}

__device__ __forceinline__ float sigmf(float x) { return 1.f / (1.f + __expf(-x)); }

// ---------------- elementwise helpers ----------------

__global__ __launch_bounds__(256) void f2bf_kernel(const float* __restrict__ in,
                                                   __hip_bfloat16* __restrict__ out, int n) {
    int i = blockIdx.x * 256 + threadIdx.x;
    if (i < n) out[i] = __float2bfloat16(in[i]);
}

__global__ __launch_bounds__(256) void gather_emb_kernel(const float* __restrict__ tab,
                                                         const int* __restrict__ cap,
                                                         __hip_bfloat16* __restrict__ out) {
    int i = blockIdx.x * 256 + threadIdx.x;  // T*B*E total
    int e = i & (EE - 1);
    int tb = i >> 9;
    int t = tb >> 6;
    int b = tb & 63;
    int tok = cap[b * TT + t];
    out[i] = __float2bfloat16(tab[(size_t)tok * EE + e]);
}

// zero both h ping-pong buffers + barrier counter
__global__ __launch_bounds__(256) void init_kernel(__hip_bfloat16* __restrict__ hb,
                                                   int* __restrict__ bar) {
    int i = blockIdx.x * 256 + threadIdx.x;  // 2*3*64*512 threads
    hb[i] = __float2bfloat16(0.f);
    if (i < 64) bar[i] = 0;
}

// ---------------- gemm128: C[M,N] = A[M,K] @ B[N,K]^T (+bias), fp32 out ----------------

__global__ __launch_bounds__(256) void gemm128_kernel(
    const __hip_bfloat16* __restrict__ A,
    const __hip_bfloat16* __restrict__ Bm,
    const float* __restrict__ bias,
    float* __restrict__ C,
    int K, int N)
{
    __shared__ __align__(16) __hip_bfloat16 As[128 * 32];
    __shared__ __align__(16) __hip_bfloat16 Bs[128 * 32];

    int m0 = blockIdx.x * 128, n0 = blockIdx.y * 128;
    int tid = threadIdx.x;
    int wave = tid >> 6, lane = tid & 63;
    int wm = wave & 1, wn = wave >> 1;
    int row16 = lane & 15, quad = lane >> 4;

    int r0 = tid >> 2, cc = (tid & 3) * 8;
    int r1 = 64 + r0;
    const __hip_bfloat16* gA0 = A  + (size_t)(m0 + r0) * K + cc;
    const __hip_bfloat16* gA1 = A  + (size_t)(m0 + r1) * K + cc;
    const __hip_bfloat16* gB0 = Bm + (size_t)(n0 + r0) * K + cc;
    const __hip_bfloat16* gB1 = Bm + (size_t)(n0 + r1) * K + cc;
    __hip_bfloat16* lA0 = As + (size_t)(wave * 64) * 8;
    __hip_bfloat16* lA1 = As + (size_t)(256 + wave * 64) * 8;
    __hip_bfloat16* lB0 = Bs + (size_t)(wave * 64) * 8;
    __hip_bfloat16* lB1 = Bs + (size_t)(256 + wave * 64) * 8;

    const __hip_bfloat16* ra = As + (size_t)(wm * 64 + row16) * 32 + quad * 8;
    const __hip_bfloat16* rb = Bs + (size_t)(wn * 64 + row16) * 32 + quad * 8;

    f32x4 acc[4][4] = {};

    for (int k = 0; k < K; k += 32) {
        gload_lds16(gA0 + k, lA0);
        gload_lds16(gA1 + k, lA1);
        gload_lds16(gB0 + k, lB0);
        gload_lds16(gB1 + k, lB1);
        __syncthreads();
        bf16x8 af[4], bfr[4];
#pragma unroll
        for (int mt = 0; mt < 4; ++mt)
            af[mt] = *reinterpret_cast<const bf16x8*>(ra + mt * 16 * 32);
#pragma unroll
        for (int nt = 0; nt < 4; ++nt)
            bfr[nt] = *reinterpret_cast<const bf16x8*>(rb + nt * 16 * 32);
#pragma unroll
        for (int mt = 0; mt < 4; ++mt)
#pragma unroll
            for (int nt = 0; nt < 4; ++nt)
                acc[mt][nt] = __builtin_amdgcn_mfma_f32_16x16x32_bf16(af[mt], bfr[nt], acc[mt][nt], 0, 0, 0);
        __syncthreads();
    }

#pragma unroll
    for (int mt = 0; mt < 4; ++mt)
#pragma unroll
        for (int nt = 0; nt < 4; ++nt) {
            int col = n0 + wn * 64 + nt * 16 + row16;
            float bv = bias ? bias[col] : 0.f;
#pragma unroll
            for (int r = 0; r < 4; ++r) {
                int row = m0 + wm * 64 + mt * 16 + quad * 4 + r;
                C[(size_t)row * N + col] = acc[mt][nt][r] + bv;
            }
        }
}

// ---------------- persistent recurrence kernel ----------------
// 32 blocks x 512 thr. Block owns 16-col h slice (GRU) and 2 batches (attn).
// All data through NORMAL cached loads/stores. Grid barrier: release-RMW
// (one buffer_wbl2) -> RELAXED poll (no cache ops) -> one ACQUIRE load
// (one buffer_inv). Weights re-warm from L3 after each inv; h exchange is
// tiny (2KB dirty per block per stage). 3 grid barriers per timestep.

__global__ __launch_bounds__(512) void recurrence_kernel(
    const float* __restrict__ GI0,            // [1280][1536] = xemb @ Wih0^T
    const __hip_bfloat16* __restrict__ wih,   // [3][1536][512]
    const __hip_bfloat16* __restrict__ whh,   // [3][1536][512]
    const float* __restrict__ bih,            // [3][1536]
    const float* __restrict__ bhh,
    const __hip_bfloat16* __restrict__ wq,    // [512][512] (in_proj rows 0..511)
    const float* __restrict__ bq,
    const __hip_bfloat16* __restrict__ wo,    // [512][512]
    const float* __restrict__ bo,
    const float* __restrict__ KV,             // [4096][1024] fp32 (K | V)
    __hip_bfloat16* __restrict__ hb,          // [2][3][64][512] bf16 ping-pong
    __hip_bfloat16* __restrict__ AO,          // [1280][512] (row = b*T + t)
    int* __restrict__ bar)
{
    __shared__ float smem[24 * 544];  // parts[24][32][17] padded; attn aliases low 12KB

    const int tid = threadIdx.x;
    const int w = tid >> 6, lane = tid & 63;
    const int row16 = lane & 15, quad = lane >> 4;
    const int blk = blockIdx.x;
    const int c0 = blk * 16;
    const size_t HS = (size_t)64 * 512;

    f32x4 h0r = {0.f, 0.f, 0.f, 0.f}, h1r = h0r, h2r = h0r;

    int lgen = 0;
    auto gridbar = [&]() {
        __syncthreads();  // drains vmcnt: all block stores are at least in L2
        if (tid == 0) {
            lgen++;
            // release: writeback this XCD's dirty L2 lines once, then bump
            __hip_atomic_fetch_add(&bar[0], 1, __ATOMIC_RELEASE, __HIP_MEMORY_SCOPE_AGENT);
            // relaxed poll: NO cache maintenance per iteration
            while (__hip_atomic_load(&bar[0], __ATOMIC_RELAXED, __HIP_MEMORY_SCOPE_AGENT) < NBLK * lgen)
                __builtin_amdgcn_s_sleep(2);
            // acquire: one invalidate so subsequent loads see other blocks' writes
            (void)__hip_atomic_load(&bar[0], __ATOMIC_ACQUIRE, __HIP_MEMORY_SCOPE_AGENT);
        }
        __syncthreads();
    };

#define PART(s, r, c) smem[(s) * 544 + (r) * 17 + (c)]

    auto gru_stage = [&](auto LC, int t, int cur) {
        constexpr int l = decltype(LC)::value;
        const int nxt = cur ^ 1;
        const __hip_bfloat16* hown = hb + (size_t)(cur * 3 + l) * HS;
        const __hip_bfloat16* xin  = l ? hb + (size_t)(nxt * 3 + (l - 1)) * HS : hown;
        const __hip_bfloat16* Wihl = wih + (size_t)l * 1536 * 512;
        const __hip_bfloat16* Whhl = whh + (size_t)l * 1536 * 512;

        // wave job: l==0: (rh, kseg/4) over Whh only; l>0: (src, rh, kseg/2)
        int src, rh, kseg, koff;
        constexpr int nk = l ? 8 : 4;
        if (l) { src = w >> 2; rh = (w >> 1) & 1; kseg = w & 1; koff = kseg * 256; }
        else   { src = 1;      rh = w >> 2;       kseg = w & 3; koff = kseg * 128; }

        const __hip_bfloat16* Ab = (src ? hown : xin) + (size_t)(rh * 32) * 512 + koff;
        const __hip_bfloat16* Wm = src ? Whhl : Wihl;
        const __hip_bfloat16* pa0 = Ab + (size_t)row16 * 512 + quad * 8;
        const __hip_bfloat16* pa1 = pa0 + (size_t)16 * 512;
        const __hip_bfloat16* pw  = Wm + (size_t)(c0 + row16) * 512 + quad * 8 + koff;

        f32x4 acc[3][2] = {};
#pragma unroll
        for (int kg = 0; kg < nk; kg += 2) {
            int kb = kg * 32;
            bf16x8 a00 = *reinterpret_cast<const bf16x8*>(pa0 + kb);
            bf16x8 a01 = *reinterpret_cast<const bf16x8*>(pa0 + kb + 32);
            bf16x8 a10 = *reinterpret_cast<const bf16x8*>(pa1 + kb);
            bf16x8 a11 = *reinterpret_cast<const bf16x8*>(pa1 + kb + 32);
#pragma unroll
            for (int g = 0; g < 3; ++g) {
                bf16x8 w0 = *reinterpret_cast<const bf16x8*>(pw + (size_t)g * 262144 + kb);
                bf16x8 w1 = *reinterpret_cast<const bf16x8*>(pw + (size_t)g * 262144 + kb + 32);
                acc[g][0] = __builtin_amdgcn_mfma_f32_16x16x32_bf16(a00, w0, acc[g][0], 0, 0, 0);
                acc[g][1] = __builtin_amdgcn_mfma_f32_16x16x32_bf16(a10, w0, acc[g][1], 0, 0, 0);
                acc[g][0] = __builtin_amdgcn_mfma_f32_16x16x32_bf16(a01, w1, acc[g][0], 0, 0, 0);
                acc[g][1] = __builtin_amdgcn_mfma_f32_16x16x32_bf16(a11, w1, acc[g][1], 0, 0, 0);
            }
        }
#pragma unroll
        for (int g = 0; g < 3; ++g) {
            int slot = l ? (g * 8 + src * 4 + rh * 2 + kseg) : (g * 8 + rh * 4 + kseg);
#pragma unroll
            for (int mf = 0; mf < 2; ++mf)
#pragma unroll
                for (int r = 0; r < 4; ++r)
                    PART(slot, mf * 16 + quad * 4 + r, row16) = acc[g][mf][r];
        }
        __syncthreads();

        if (tid < 256) {
            int row = tid >> 2, cg = tid & 3;
            int rh2 = row >> 5, lr = row & 31;
            const float* bihl = bih + l * 1536;
            const float* bhhl = bhh + l * 1536;
            f32x4& hr = (l == 0) ? h0r : (l == 1) ? h1r : h2r;
            f32x4 gi4[3];
            if (!l) {
                const float* gp = GI0 + (size_t)(t * 64 + row) * 1536 + c0 + cg * 4;
#pragma unroll
                for (int g = 0; g < 3; ++g)
                    gi4[g] = *reinterpret_cast<const f32x4*>(gp + g * 512);
            }
            union { unsigned short us[4]; u64 u; } pk;
#pragma unroll
            for (int cc = 0; cc < 4; ++cc) {
                int col16 = cg * 4 + cc, col = c0 + col16;
                float gi[3], gh[3];
#pragma unroll
                for (int g = 0; g < 3; ++g) {
                    if (l) {
                        gi[g] = PART(g * 8 + rh2 * 2, lr, col16) + PART(g * 8 + rh2 * 2 + 1, lr, col16);
                        gh[g] = PART(g * 8 + 4 + rh2 * 2, lr, col16) + PART(g * 8 + 4 + rh2 * 2 + 1, lr, col16);
                    } else {
                        gh[g] = PART(g * 8 + rh2 * 4, lr, col16) + PART(g * 8 + rh2 * 4 + 1, lr, col16) +
                                PART(g * 8 + rh2 * 4 + 2, lr, col16) + PART(g * 8 + rh2 * 4 + 3, lr, col16);
                        gi[g] = gi4[g][cc];
                    }
                }
                float rr = sigmf(gi[0] + gh[0] + bihl[col] + bhhl[col]);
                float zz = sigmf(gi[1] + gh[1] + bihl[512 + col] + bhhl[512 + col]);
                float nn = tanhf(gi[2] + bihl[1024 + col] + rr * (gh[2] + bhhl[1024 + col]));
                float hnew = (1.f - zz) * nn + zz * hr[cc];
                hr[cc] = hnew;
                __hip_bfloat16 hv = __float2bfloat16(hnew);
                pk.us[cc] = *reinterpret_cast<unsigned short*>(&hv);
            }
            *reinterpret_cast<u64*>(hb + (size_t)(nxt * 3 + l) * HS + (size_t)row * 512 + c0 + cg * 4) = pk.u;
        }
    };

    // fused q-proj + attention + out-proj; block owns batches 2*blk, 2*blk+1
    auto attn_stage = [&](int t, int nxt) {
        float* h2f = smem;          // [2][512]
        float* qs  = smem + 1024;   // [2][512]
        float* cs  = smem + 2048;   // [2][512]
        const int b0 = blk * 2;
        const __hip_bfloat16* h2b = hb + (size_t)(nxt * 3 + 2) * HS;

        if (tid < 128) {
            int bl = tid >> 6, k8 = tid & 63;
            bf16x8 hv = *reinterpret_cast<const bf16x8*>(h2b + (size_t)(b0 + bl) * 512 + k8 * 8);
            float* d = h2f + bl * 512 + k8 * 8;
#pragma unroll
            for (int e = 0; e < 8; ++e) d[e] = (float)hv[e];
        }
        __syncthreads();

        // q[bl][tid] = bq + h2 . wq_row(tid)
#pragma unroll 1
        for (int bl = 0; bl < 2; ++bl) {
            float s = bq[tid];
            const __hip_bfloat16* wrow = wq + (size_t)tid * 512;
            const float* hs = h2f + bl * 512;
#pragma unroll 4
            for (int k8 = 0; k8 < 64; ++k8) {
                bf16x8 wv = *reinterpret_cast<const bf16x8*>(wrow + k8 * 8);
#pragma unroll
                for (int e = 0; e < 8; ++e) s += hs[k8 * 8 + e] * (float)wv[e];
            }
            qs[bl * 512 + tid] = s;
        }
        __syncthreads();

        // per (bl, head=w): softmax attention; lane = kv pos, then lane = dim
#pragma unroll 1
        for (int bl = 0; bl < 2; ++bl) {
            int b = b0 + bl;
            const float* qh = qs + bl * 512 + w * 64;
            const float* kr = KV + (size_t)(b * 64 + lane) * 1024 + w * 64;
            float sc = 0.f;
#pragma unroll
            for (int d4 = 0; d4 < 16; ++d4) {
                f32x4 kv4 = *reinterpret_cast<const f32x4*>(kr + d4 * 4);
                f32x4 qv4 = *reinterpret_cast<const f32x4*>(qh + d4 * 4);
                sc += qv4[0] * kv4[0] + qv4[1] * kv4[1] + qv4[2] * kv4[2] + qv4[3] * kv4[3];
            }
            sc *= 0.125f;  // 1/sqrt(64)
            float m = sc;
            for (int off = 32; off; off >>= 1) m = fmaxf(m, __shfl_xor(m, off, 64));
            float e = __expf(sc - m);
            float s = e;
            for (int off = 32; off; off >>= 1) s += __shfl_xor(s, off, 64);
            float p = e / s;
            const float* vb = KV + (size_t)(b * 64) * 1024 + 512 + w * 64 + lane;
            float acc = 0.f;
#pragma unroll
            for (int si = 0; si < 64; ++si)
                acc += __shfl(p, si, 64) * vb[(size_t)si * 1024];
            cs[bl * 512 + w * 64 + lane] = acc;
        }
        __syncthreads();

        // AO[(b*T+t)][tid] = bo + ctx . wo_row(tid)
#pragma unroll 1
        for (int bl = 0; bl < 2; ++bl) {
            float s = bo[tid];
            const __hip_bfloat16* wrow = wo + (size_t)tid * 512;
            const float* csr = cs + bl * 512;
#pragma unroll 4
            for (int k8 = 0; k8 < 64; ++k8) {
                bf16x8 wv = *reinterpret_cast<const bf16x8*>(wrow + k8 * 8);
#pragma unroll
                for (int e = 0; e < 8; ++e) s += csr[k8 * 8 + e] * (float)wv[e];
            }
            AO[((size_t)(b0 + bl) * TT + t) * 512 + tid] = __float2bfloat16(s);
        }
        __syncthreads();  // protect smem before next step's store_parts
    };

#pragma unroll 1
    for (int t = 0; t < TT; ++t) {
        int cur = t & 1, nxt = cur ^ 1;
        gru_stage(IC<0>{}, t, cur); gridbar();
        gru_stage(IC<1>{}, t, cur); gridbar();
        gru_stage(IC<2>{}, t, cur); gridbar();
        attn_stage(t, nxt);
        // no trailing grid barrier: next step's l0/l1 touch only layer-0/1 buffers;
        // hb[*][2] WAR is >=3 barriers away; AO/GI0/KV have no in-kernel readers/writers.
    }
#undef PART
}

// ---------------- host ----------------

extern "C" void kernel_launch(void* const* d_in, const int* in_sizes, int n_in,
                              void* d_out, int out_size, void* d_ws, size_t ws_size,
                              hipStream_t stream) {
    const float* enc        = (const float*)d_in[0];
    const int*   cap        = (const int*)d_in[1];
    const float* emb_tab    = (const float*)d_in[2];
    const float* w_ih       = (const float*)d_in[3];
    const float* w_hh       = (const float*)d_in[4];
    const float* b_ih       = (const float*)d_in[5];
    const float* b_hh       = (const float*)d_in[6];
    const float* in_proj_w  = (const float*)d_in[7];
    const float* in_proj_b  = (const float*)d_in[8];
    const float* out_proj_w = (const float*)d_in[9];
    const float* out_proj_b = (const float*)d_in[10];
    const float* fc_w       = (const float*)d_in[11];
    const float* fc_b       = (const float*)d_in[12];
    float* out = (float*)d_out;

    char* p = (char*)d_ws;
    auto alloc = [&](size_t bytes) {
        char* r = p;
        p += (bytes + 255) & ~(size_t)255;
        return r;
    };
    __hip_bfloat16* fcw_bf  = (__hip_bfloat16*)alloc((size_t)VV * HH * 2);
    __hip_bfloat16* enc_bf  = (__hip_bfloat16*)alloc((size_t)BB * 64 * HH * 2);
    __hip_bfloat16* inp_bf  = (__hip_bfloat16*)alloc((size_t)1536 * 512 * 2);
    __hip_bfloat16* wih_bf  = (__hip_bfloat16*)alloc((size_t)3 * 1536 * 512 * 2);
    __hip_bfloat16* whh_bf  = (__hip_bfloat16*)alloc((size_t)3 * 1536 * 512 * 2);
    __hip_bfloat16* wo_bf   = (__hip_bfloat16*)alloc((size_t)512 * 512 * 2);
    __hip_bfloat16* xemb_bf = (__hip_bfloat16*)alloc((size_t)TT * BB * EE * 2);
    float* KV   = (float*)alloc((size_t)4096 * 1024 * 4);
    float* GI0  = (float*)alloc((size_t)1280 * 1536 * 4);
    __hip_bfloat16* hb = (__hip_bfloat16*)alloc((size_t)2 * 3 * 64 * 512 * 2);
    __hip_bfloat16* AO = (__hip_bfloat16*)alloc((size_t)1280 * 512 * 2);
    int* bar = (int*)alloc(256);

    auto cvt = [&](const float* src, __hip_bfloat16* dst, int n) {
        f2bf_kernel<<<(n + 255) / 256, 256, 0, stream>>>(src, dst, n);
    };
    cvt(fc_w, fcw_bf, VV * HH);
    cvt(enc, enc_bf, BB * 64 * HH);
    cvt(in_proj_w, inp_bf, 1536 * 512);
    cvt(w_ih, wih_bf, 3 * 1536 * 512);
    cvt(w_hh, whh_bf, 3 * 1536 * 512);
    cvt(out_proj_w, wo_bf, 512 * 512);
    gather_emb_kernel<<<(TT * BB * EE) / 256, 256, 0, stream>>>(emb_tab, cap, xemb_bf);
    init_kernel<<<(2 * 3 * 64 * 512) / 256, 256, 0, stream>>>(hb, bar);

    // KV = enc @ [Wk;Wv]^T + [bk;bv]   (4096 x 1024, K=512)
    gemm128_kernel<<<dim3(32, 8), 256, 0, stream>>>(
        enc_bf, inp_bf + 512 * 512, in_proj_b + 512, KV, 512, 1024);

    // GI0 = xemb @ Wih0^T   (1280 x 1536, no bias)
    gemm128_kernel<<<dim3(10, 12), 256, 0, stream>>>(
        xemb_bf, wih_bf, nullptr, GI0, 512, 1536);

    // whole recurrence in one persistent kernel
    recurrence_kernel<<<NBLK, 512, 0, stream>>>(
        GI0, wih_bf, whh_bf, b_ih, b_hh,
        inp_bf, in_proj_b, wo_bf, out_proj_b,
        KV, hb, AO, bar);

    // logits = AO @ fc_w^T + fc_b   (1280 x 32000) -> d_out (B,T,V)
    gemm128_kernel<<<dim3(10, 250), 256, 0, stream>>>(
        AO, fcw_bf, fc_b, out, 512, VV);
}

// Round 5
// 2776.124 us; speedup vs baseline: 1.3431x; 1.2371x over previous
//
#include <hip/hip_runtime.h>
#include <hip/hip_bf16.h>

#define TT 20
#define BB 64
#define HH 512
#define EE 512
#define VV 32000
#define NBLK 32

typedef __bf16 bf16x8 __attribute__((ext_vector_type(8)));
typedef float f32x4 __attribute__((ext_vector_type(4)));
typedef unsigned long long u64;

template <int L> struct IC { static constexpr int value = L; };

__device__ __forceinline__ void gload_lds16(const __hip_bfloat16* g, __hip_bfloat16* l) {
    __builtin_amdgcn_global_load_lds((const __attribute__((address_space(1))) void*)g,
                                     (__attribute__((address_space(3))) void*)l, 16, 0, 0);
}

__device__ __forceinline__ float sigmf(float x) { return 1.f / (1.f + __expf(-x)); }

// coherent (L2-bypass sc0sc1, NO cache maintenance) accesses for cross-block state
__device__ __forceinline__ bf16x8 cload8(const __hip_bfloat16* p) {
    union { u64 q[2]; bf16x8 v; } u;
    u.q[0] = __hip_atomic_load((const u64*)p, __ATOMIC_RELAXED, __HIP_MEMORY_SCOPE_AGENT);
    u.q[1] = __hip_atomic_load((const u64*)p + 1, __ATOMIC_RELAXED, __HIP_MEMORY_SCOPE_AGENT);
    return u.v;
}
__device__ __forceinline__ void cstore8B(void* p, u64 v) {
    __hip_atomic_store((u64*)p, v, __ATOMIC_RELAXED, __HIP_MEMORY_SCOPE_AGENT);
}
__device__ __forceinline__ void cstore4B(void* p, unsigned v) {
    __hip_atomic_store((unsigned*)p, v, __ATOMIC_RELAXED, __HIP_MEMORY_SCOPE_AGENT);
}
__device__ __forceinline__ u64 cload8B(const void* p) {
    return __hip_atomic_load((const u64*)p, __ATOMIC_RELAXED, __HIP_MEMORY_SCOPE_AGENT);
}

// ---------------- elementwise helpers ----------------

__global__ __launch_bounds__(256) void f2bf_kernel(const float* __restrict__ in,
                                                   __hip_bfloat16* __restrict__ out, int n) {
    int i = blockIdx.x * 256 + threadIdx.x;
    if (i < n) out[i] = __float2bfloat16(in[i]);
}

__global__ __launch_bounds__(256) void gather_emb_kernel(const float* __restrict__ tab,
                                                         const int* __restrict__ cap,
                                                         __hip_bfloat16* __restrict__ out) {
    int i = blockIdx.x * 256 + threadIdx.x;  // T*B*E total
    int e = i & (EE - 1);
    int tb = i >> 9;
    int t = tb >> 6;
    int b = tb & 63;
    int tok = cap[b * TT + t];
    out[i] = __float2bfloat16(tab[(size_t)tok * EE + e]);
}

// zero both h ping-pong buffers + barrier counter
__global__ __launch_bounds__(256) void init_kernel(__hip_bfloat16* __restrict__ hb,
                                                   int* __restrict__ bar) {
    int i = blockIdx.x * 256 + threadIdx.x;  // 2*3*64*512 threads
    hb[i] = __float2bfloat16(0.f);
    if (i < 64) bar[i] = 0;
}

// ---------------- gemm128: C[M,N] = A[M,K] @ B[N,K]^T (+bias), fp32 out ----------------

__global__ __launch_bounds__(256) void gemm128_kernel(
    const __hip_bfloat16* __restrict__ A,
    const __hip_bfloat16* __restrict__ Bm,
    const float* __restrict__ bias,
    float* __restrict__ C,
    int K, int N)
{
    __shared__ __align__(16) __hip_bfloat16 As[128 * 32];
    __shared__ __align__(16) __hip_bfloat16 Bs[128 * 32];

    int m0 = blockIdx.x * 128, n0 = blockIdx.y * 128;
    int tid = threadIdx.x;
    int wave = tid >> 6, lane = tid & 63;
    int wm = wave & 1, wn = wave >> 1;
    int row16 = lane & 15, quad = lane >> 4;

    int r0 = tid >> 2, cc = (tid & 3) * 8;
    int r1 = 64 + r0;
    const __hip_bfloat16* gA0 = A  + (size_t)(m0 + r0) * K + cc;
    const __hip_bfloat16* gA1 = A  + (size_t)(m0 + r1) * K + cc;
    const __hip_bfloat16* gB0 = Bm + (size_t)(n0 + r0) * K + cc;
    const __hip_bfloat16* gB1 = Bm + (size_t)(n0 + r1) * K + cc;
    __hip_bfloat16* lA0 = As + (size_t)(wave * 64) * 8;
    __hip_bfloat16* lA1 = As + (size_t)(256 + wave * 64) * 8;
    __hip_bfloat16* lB0 = Bs + (size_t)(wave * 64) * 8;
    __hip_bfloat16* lB1 = Bs + (size_t)(256 + wave * 64) * 8;

    const __hip_bfloat16* ra = As + (size_t)(wm * 64 + row16) * 32 + quad * 8;
    const __hip_bfloat16* rb = Bs + (size_t)(wn * 64 + row16) * 32 + quad * 8;

    f32x4 acc[4][4] = {};

    for (int k = 0; k < K; k += 32) {
        gload_lds16(gA0 + k, lA0);
        gload_lds16(gA1 + k, lA1);
        gload_lds16(gB0 + k, lB0);
        gload_lds16(gB1 + k, lB1);
        __syncthreads();
        bf16x8 af[4], bfr[4];
#pragma unroll
        for (int mt = 0; mt < 4; ++mt)
            af[mt] = *reinterpret_cast<const bf16x8*>(ra + mt * 16 * 32);
#pragma unroll
        for (int nt = 0; nt < 4; ++nt)
            bfr[nt] = *reinterpret_cast<const bf16x8*>(rb + nt * 16 * 32);
#pragma unroll
        for (int mt = 0; mt < 4; ++mt)
#pragma unroll
            for (int nt = 0; nt < 4; ++nt)
                acc[mt][nt] = __builtin_amdgcn_mfma_f32_16x16x32_bf16(af[mt], bfr[nt], acc[mt][nt], 0, 0, 0);
        __syncthreads();
    }

#pragma unroll
    for (int mt = 0; mt < 4; ++mt)
#pragma unroll
        for (int nt = 0; nt < 4; ++nt) {
            int col = n0 + wn * 64 + nt * 16 + row16;
            float bv = bias ? bias[col] : 0.f;
#pragma unroll
            for (int r = 0; r < 4; ++r) {
                int row = m0 + wm * 64 + mt * 16 + quad * 4 + r;
                C[(size_t)row * N + col] = acc[mt][nt][r] + bv;
            }
        }
}

// ---------------- persistent recurrence kernel ----------------
// 32 blocks x 512 thr. Block owns 16-col slice of every 64x512 projection
// output (GRU h, q, AO); attn per (b,head) wave. Barrier = relaxed-only
// monotonic counter (NO acquire/release -> L2 never invalidated -> weights/
// KV/GI0 L2-resident all kernel). Cross-block state (hb, q, ctx) through
// sc0sc1 coherent atomics, BULK-preloaded into fragment registers before
// each MFMA loop (full MLP, never interleaved with compute). 5 barriers/step.

__global__ __launch_bounds__(512) void recurrence_kernel(
    const float* __restrict__ GI0,            // [1280][1536] = xemb @ Wih0^T
    const __hip_bfloat16* __restrict__ wih,   // [3][1536][512]
    const __hip_bfloat16* __restrict__ whh,   // [3][1536][512]
    const float* __restrict__ bih,            // [3][1536]
    const float* __restrict__ bhh,
    const __hip_bfloat16* __restrict__ wq,    // [512][512] (in_proj rows 0..511)
    const float* __restrict__ bq,
    const __hip_bfloat16* __restrict__ wo,    // [512][512]
    const float* __restrict__ bo,
    const float* __restrict__ KV,             // [4096][1024] fp32 (K | V)
    __hip_bfloat16* __restrict__ hb,          // [2][3][64][512] bf16 ping-pong
    float* __restrict__ qg,                   // [64][512] fp32 (coherent)
    __hip_bfloat16* __restrict__ ctxg,        // [64][512] bf16 (coherent)
    __hip_bfloat16* __restrict__ AO,          // [1280][512] (row = b*T + t)
    int* __restrict__ bar)
{
    __shared__ float smem[24 * 544];  // parts[24][32][17]; attn aliases low 4KB

    const int tid = threadIdx.x;
    const int w = tid >> 6, lane = tid & 63;
    const int row16 = lane & 15, quad = lane >> 4;
    const int blk = blockIdx.x;
    const int c0 = blk * 16;
    const size_t HS = (size_t)64 * 512;

    f32x4 h0r = {0.f, 0.f, 0.f, 0.f}, h1r = h0r, h2r = h0r;

    int lgen = 0;
    auto gridbar = [&]() {
        asm volatile("s_waitcnt vmcnt(0)" ::: "memory");  // coherent stores globally visible
        __syncthreads();
        if (tid == 0) {
            lgen++;
            __hip_atomic_fetch_add(&bar[0], 1, __ATOMIC_RELAXED, __HIP_MEMORY_SCOPE_AGENT);
            while (__hip_atomic_load(&bar[0], __ATOMIC_RELAXED, __HIP_MEMORY_SCOPE_AGENT) < NBLK * lgen)
                __builtin_amdgcn_s_sleep(1);
        }
        __syncthreads();
    };

#define PART(s, r, c) smem[(s) * 544 + (r) * 17 + (c)]

    auto gru_stage = [&](auto LC, int t, int cur) {
        constexpr int l = decltype(LC)::value;
        const int nxt = cur ^ 1;
        const __hip_bfloat16* hown = hb + (size_t)(cur * 3 + l) * HS;
        const __hip_bfloat16* xin  = l ? hb + (size_t)(nxt * 3 + (l - 1)) * HS : hown;
        const __hip_bfloat16* Wihl = wih + (size_t)l * 1536 * 512;
        const __hip_bfloat16* Whhl = whh + (size_t)l * 1536 * 512;

        // wave job: l==0: (rh=w>>2, kseg=w&3) over Whh only; l>0: (src=w>>2, rh, kseg)
        int src, rh, kseg, koff;
        constexpr int nk = l ? 8 : 4;
        if (l) { src = w >> 2; rh = (w >> 1) & 1; kseg = w & 1; koff = kseg * 256; }
        else   { src = 1;      rh = w >> 2;       kseg = w & 3; koff = kseg * 128; }

        // bulk coherent preload of A fragments into registers (high MLP)
        const __hip_bfloat16* Asrc = src ? hown : xin;
        const __hip_bfloat16* pa = Asrc + (size_t)(rh * 32 + row16) * 512 + koff + quad * 8;
        bf16x8 af0[nk], af1[nk];
#pragma unroll
        for (int kk = 0; kk < nk; ++kk) {
            af0[kk] = cload8(pa + kk * 32);
            af1[kk] = cload8(pa + (size_t)16 * 512 + kk * 32);
        }

        const __hip_bfloat16* pw = (src ? Whhl : Wihl) + (size_t)(c0 + row16) * 512 + koff + quad * 8;
        f32x4 acc[3][2] = {};
#pragma unroll
        for (int kk = 0; kk < nk; ++kk) {
            int kb = kk * 32;
#pragma unroll
            for (int g = 0; g < 3; ++g) {
                bf16x8 wv = *reinterpret_cast<const bf16x8*>(pw + (size_t)g * 262144 + kb);
                acc[g][0] = __builtin_amdgcn_mfma_f32_16x16x32_bf16(af0[kk], wv, acc[g][0], 0, 0, 0);
                acc[g][1] = __builtin_amdgcn_mfma_f32_16x16x32_bf16(af1[kk], wv, acc[g][1], 0, 0, 0);
            }
        }
#pragma unroll
        for (int g = 0; g < 3; ++g) {
            int slot = l ? (g * 8 + src * 4 + rh * 2 + kseg) : (g * 8 + rh * 4 + kseg);
#pragma unroll
            for (int mf = 0; mf < 2; ++mf)
#pragma unroll
                for (int r = 0; r < 4; ++r)
                    PART(slot, mf * 16 + quad * 4 + r, row16) = (mf ? acc[g][1][r] : acc[g][0][r]);
        }
        __syncthreads();

        if (tid < 256) {
            int row = tid >> 2, cg = tid & 3;
            int rh2 = row >> 5, lr = row & 31;
            const float* bihl = bih + l * 1536;
            const float* bhhl = bhh + l * 1536;
            f32x4& hr = (l == 0) ? h0r : (l == 1) ? h1r : h2r;
            f32x4 gi4[3];
            if (!l) {
                const float* gp = GI0 + (size_t)(t * 64 + row) * 1536 + c0 + cg * 4;
#pragma unroll
                for (int g = 0; g < 3; ++g)
                    gi4[g] = *reinterpret_cast<const f32x4*>(gp + g * 512);
            }
            union { unsigned short us[4]; u64 u; } pk;
#pragma unroll
            for (int cc = 0; cc < 4; ++cc) {
                int col16 = cg * 4 + cc, col = c0 + col16;
                float gi[3], gh[3];
#pragma unroll
                for (int g = 0; g < 3; ++g) {
                    if (l) {
                        gi[g] = PART(g * 8 + rh2 * 2, lr, col16) + PART(g * 8 + rh2 * 2 + 1, lr, col16);
                        gh[g] = PART(g * 8 + 4 + rh2 * 2, lr, col16) + PART(g * 8 + 4 + rh2 * 2 + 1, lr, col16);
                    } else {
                        gh[g] = PART(g * 8 + rh2 * 4, lr, col16) + PART(g * 8 + rh2 * 4 + 1, lr, col16) +
                                PART(g * 8 + rh2 * 4 + 2, lr, col16) + PART(g * 8 + rh2 * 4 + 3, lr, col16);
                        gi[g] = gi4[g][cc];
                    }
                }
                float rr = sigmf(gi[0] + gh[0] + bihl[col] + bhhl[col]);
                float zz = sigmf(gi[1] + gh[1] + bihl[512 + col] + bhhl[512 + col]);
                float nn = tanhf(gi[2] + bihl[1024 + col] + rr * (gh[2] + bhhl[1024 + col]));
                float hnew = (1.f - zz) * nn + zz * hr[cc];
                hr[cc] = hnew;
                __hip_bfloat16 hv = __float2bfloat16(hnew);
                pk.us[cc] = *reinterpret_cast<unsigned short*>(&hv);
            }
            cstore8B(hb + (size_t)(nxt * 3 + l) * HS + (size_t)row * 512 + c0 + cg * 4, pk.u);
        }
        __syncthreads();
    };

    // col-sliced 64x512 projection (K=512): A coherent bf16, W slice L2-cached.
    // to_q: fp32 -> qg; else bf16 -> AO row (b*T + t).
    auto proj_stage = [&](const __hip_bfloat16* Asrc, const __hip_bfloat16* Wm,
                          const float* bias, bool to_q, int t) {
        int rh = w >> 2, kseg = w & 3, koff = kseg * 128;
        const __hip_bfloat16* pa = Asrc + (size_t)(rh * 32 + row16) * 512 + koff + quad * 8;
        bf16x8 af0[4], af1[4];
#pragma unroll
        for (int kk = 0; kk < 4; ++kk) {
            af0[kk] = cload8(pa + kk * 32);
            af1[kk] = cload8(pa + (size_t)16 * 512 + kk * 32);
        }
        const __hip_bfloat16* pw = Wm + (size_t)(c0 + row16) * 512 + koff + quad * 8;
        f32x4 a0 = {0.f, 0.f, 0.f, 0.f}, a1 = a0;
#pragma unroll
        for (int kk = 0; kk < 4; ++kk) {
            bf16x8 wv = *reinterpret_cast<const bf16x8*>(pw + kk * 32);
            a0 = __builtin_amdgcn_mfma_f32_16x16x32_bf16(af0[kk], wv, a0, 0, 0, 0);
            a1 = __builtin_amdgcn_mfma_f32_16x16x32_bf16(af1[kk], wv, a1, 0, 0, 0);
        }
#pragma unroll
        for (int r = 0; r < 4; ++r) {
            PART(w, quad * 4 + r, row16) = a0[r];
            PART(w, 16 + quad * 4 + r, row16) = a1[r];
        }
        __syncthreads();
        if (tid < 256) {
            int row = tid >> 2, cg = tid & 3;
            int rh2 = row >> 5, lr = row & 31;
            float v[4];
#pragma unroll
            for (int cc = 0; cc < 4; ++cc) {
                int col16 = cg * 4 + cc;
                float s = bias[c0 + col16];
#pragma unroll
                for (int ks = 0; ks < 4; ++ks) s += PART(rh2 * 4 + ks, lr, col16);
                v[cc] = s;
            }
            if (to_q) {
                float* dst = qg + (size_t)row * 512 + c0 + cg * 4;
                union { float f[2]; u64 u; } p0, p1;
                p0.f[0] = v[0]; p0.f[1] = v[1];
                p1.f[0] = v[2]; p1.f[1] = v[3];
                cstore8B(dst, p0.u);
                cstore8B(dst + 2, p1.u);
            } else {
                union { unsigned short us[4]; u64 u; } pk;
#pragma unroll
                for (int cc = 0; cc < 4; ++cc) {
                    __hip_bfloat16 hv = __float2bfloat16(v[cc]);
                    pk.us[cc] = *reinterpret_cast<unsigned short*>(&hv);
                }
                cstore8B(AO + ((size_t)row * TT + t) * 512 + c0 + cg * 4, pk.u);
            }
        }
        __syncthreads();
    };

    // per-(b,head) softmax attention; block handles batches blk and blk+32
    auto attn_stage = [&]() {
        float* qls = smem;  // [2][512]
        if (tid < 256) {
            int rr = tid >> 7, off = (tid & 127) * 4;
            const float* src = qg + (size_t)(blk + rr * 32) * 512 + off;
            union { u64 u; float f[2]; } lo, hi;
            lo.u = cload8B(src);
            hi.u = cload8B(src + 2);
            float* d = qls + rr * 512 + off;
            d[0] = lo.f[0]; d[1] = lo.f[1]; d[2] = hi.f[0]; d[3] = hi.f[1];
        }
        __syncthreads();
#pragma unroll 1
        for (int rr = 0; rr < 2; ++rr) {
            int b = blk + rr * 32;
            const float* qh = qls + rr * 512 + w * 64;
            const float* kr = KV + (size_t)(b * 64 + lane) * 1024 + w * 64;
            float sc = 0.f;
#pragma unroll
            for (int d4 = 0; d4 < 16; ++d4) {
                f32x4 kv4 = *reinterpret_cast<const f32x4*>(kr + d4 * 4);
                f32x4 qv4 = *reinterpret_cast<const f32x4*>(qh + d4 * 4);
                sc += qv4[0] * kv4[0] + qv4[1] * kv4[1] + qv4[2] * kv4[2] + qv4[3] * kv4[3];
            }
            sc *= 0.125f;  // 1/sqrt(64)
            float m = sc;
            for (int off = 32; off; off >>= 1) m = fmaxf(m, __shfl_xor(m, off, 64));
            float e = __expf(sc - m);
            float s = e;
            for (int off = 32; off; off >>= 1) s += __shfl_xor(s, off, 64);
            float p = e / s;
            const float* vb = KV + (size_t)(b * 64) * 1024 + 512 + w * 64 + lane;
            float acc = 0.f;
#pragma unroll
            for (int si = 0; si < 64; ++si)
                acc += __shfl(p, si, 64) * vb[(size_t)si * 1024];
            // pack lane pairs -> 4B coherent store of 2 bf16
            float hi = __shfl_down(acc, 1, 64);
            if (!(lane & 1)) {
                __hip_bfloat16 e0 = __float2bfloat16(acc), e1 = __float2bfloat16(hi);
                unsigned pk = (unsigned)*reinterpret_cast<unsigned short*>(&e0) |
                              ((unsigned)*reinterpret_cast<unsigned short*>(&e1) << 16);
                cstore4B(ctxg + (size_t)b * 512 + w * 64 + lane, pk);
            }
        }
        __syncthreads();
    };

#pragma unroll 1
    for (int t = 0; t < TT; ++t) {
        int cur = t & 1, nxt = cur ^ 1;
        gru_stage(IC<0>{}, t, cur); gridbar();
        gru_stage(IC<1>{}, t, cur); gridbar();
        gru_stage(IC<2>{}, t, cur); gridbar();
        proj_stage(hb + (size_t)(nxt * 3 + 2) * HS, wq, bq, true, t); gridbar();
        attn_stage(); gridbar();
        proj_stage(ctxg, wo, bo, false, t);
        // no trailing barrier: S1(t+1) writes hb[l0] (last read 4 barriers back);
        // ctx's next writer (S5, t+1) is >=4 barriers ahead of any S6(t) straggler.
    }
#undef PART
}

// ---------------- host ----------------

extern "C" void kernel_launch(void* const* d_in, const int* in_sizes, int n_in,
                              void* d_out, int out_size, void* d_ws, size_t ws_size,
                              hipStream_t stream) {
    const float* enc        = (const float*)d_in[0];
    const int*   cap        = (const int*)d_in[1];
    const float* emb_tab    = (const float*)d_in[2];
    const float* w_ih       = (const float*)d_in[3];
    const float* w_hh       = (const float*)d_in[4];
    const float* b_ih       = (const float*)d_in[5];
    const float* b_hh       = (const float*)d_in[6];
    const float* in_proj_w  = (const float*)d_in[7];
    const float* in_proj_b  = (const float*)d_in[8];
    const float* out_proj_w = (const float*)d_in[9];
    const float* out_proj_b = (const float*)d_in[10];
    const float* fc_w       = (const float*)d_in[11];
    const float* fc_b       = (const float*)d_in[12];
    float* out = (float*)d_out;

    char* p = (char*)d_ws;
    auto alloc = [&](size_t bytes) {
        char* r = p;
        p += (bytes + 255) & ~(size_t)255;
        return r;
    };
    __hip_bfloat16* fcw_bf  = (__hip_bfloat16*)alloc((size_t)VV * HH * 2);
    __hip_bfloat16* enc_bf  = (__hip_bfloat16*)alloc((size_t)BB * 64 * HH * 2);
    __hip_bfloat16* inp_bf  = (__hip_bfloat16*)alloc((size_t)1536 * 512 * 2);
    __hip_bfloat16* wih_bf  = (__hip_bfloat16*)alloc((size_t)3 * 1536 * 512 * 2);
    __hip_bfloat16* whh_bf  = (__hip_bfloat16*)alloc((size_t)3 * 1536 * 512 * 2);
    __hip_bfloat16* wo_bf   = (__hip_bfloat16*)alloc((size_t)512 * 512 * 2);
    __hip_bfloat16* xemb_bf = (__hip_bfloat16*)alloc((size_t)TT * BB * EE * 2);
    float* KV   = (float*)alloc((size_t)4096 * 1024 * 4);
    float* GI0  = (float*)alloc((size_t)1280 * 1536 * 4);
    __hip_bfloat16* hb = (__hip_bfloat16*)alloc((size_t)2 * 3 * 64 * 512 * 2);
    float* qg = (float*)alloc((size_t)64 * 512 * 4);
    __hip_bfloat16* ctxg = (__hip_bfloat16*)alloc((size_t)64 * 512 * 2);
    __hip_bfloat16* AO = (__hip_bfloat16*)alloc((size_t)1280 * 512 * 2);
    int* bar = (int*)alloc(256);

    auto cvt = [&](const float* src, __hip_bfloat16* dst, int n) {
        f2bf_kernel<<<(n + 255) / 256, 256, 0, stream>>>(src, dst, n);
    };
    cvt(fc_w, fcw_bf, VV * HH);
    cvt(enc, enc_bf, BB * 64 * HH);
    cvt(in_proj_w, inp_bf, 1536 * 512);
    cvt(w_ih, wih_bf, 3 * 1536 * 512);
    cvt(w_hh, whh_bf, 3 * 1536 * 512);
    cvt(out_proj_w, wo_bf, 512 * 512);
    gather_emb_kernel<<<(TT * BB * EE) / 256, 256, 0, stream>>>(emb_tab, cap, xemb_bf);
    init_kernel<<<(2 * 3 * 64 * 512) / 256, 256, 0, stream>>>(hb, bar);

    // KV = enc @ [Wk;Wv]^T + [bk;bv]   (4096 x 1024, K=512)
    gemm128_kernel<<<dim3(32, 8), 256, 0, stream>>>(
        enc_bf, inp_bf + 512 * 512, in_proj_b + 512, KV, 512, 1024);

    // GI0 = xemb @ Wih0^T   (1280 x 1536, no bias)
    gemm128_kernel<<<dim3(10, 12), 256, 0, stream>>>(
        xemb_bf, wih_bf, nullptr, GI0, 512, 1536);

    // whole recurrence in one persistent kernel
    recurrence_kernel<<<NBLK, 512, 0, stream>>>(
        GI0, wih_bf, whh_bf, b_ih, b_hh,
        inp_bf, in_proj_b, wo_bf, out_proj_b,
        KV, hb, qg, ctxg, AO, bar);

    // logits = AO @ fc_w^T + fc_b   (1280 x 32000) -> d_out (B,T,V)
    gemm128_kernel<<<dim3(10, 250), 256, 0, stream>>>(
        AO, fcw_bf, fc_b, out, 512, VV);
}

// Round 6
// 2201.597 us; speedup vs baseline: 1.6936x; 1.2610x over previous
//
#include <hip/hip_runtime.h>
#include <hip/hip_bf16.h>

#define TT 20
#define BB 64
#define HH 512
#define EE 512
#define VV 32000
#define NBLK 32

typedef __bf16 bf16x8 __attribute__((ext_vector_type(8)));
typedef float f32x4 __attribute__((ext_vector_type(4)));
typedef unsigned long long u64;

template <int L> struct IC { static constexpr int value = L; };

__device__ __forceinline__ void gload_lds16(const __hip_bfloat16* g, __hip_bfloat16* l) {
    __builtin_amdgcn_global_load_lds((const __attribute__((address_space(1))) void*)g,
                                     (__attribute__((address_space(3))) void*)l, 16, 0, 0);
}

__device__ __forceinline__ float sigmf(float x) { return 1.f / (1.f + __expf(-x)); }

// sc0sc1 write-around stores (coherence-point visible; never dirty local L2)
__device__ __forceinline__ void cstore8B(void* p, u64 v) {
    __hip_atomic_store((u64*)p, v, __ATOMIC_RELAXED, __HIP_MEMORY_SCOPE_AGENT);
}
__device__ __forceinline__ void cstore4B(void* p, unsigned v) {
    __hip_atomic_store((unsigned*)p, v, __ATOMIC_RELAXED, __HIP_MEMORY_SCOPE_AGENT);
}

// ---------------- elementwise helpers ----------------

__global__ __launch_bounds__(256) void f2bf_kernel(const float* __restrict__ in,
                                                   __hip_bfloat16* __restrict__ out, int n) {
    int i = blockIdx.x * 256 + threadIdx.x;
    if (i < n) out[i] = __float2bfloat16(in[i]);
}

__global__ __launch_bounds__(256) void gather_emb_kernel(const float* __restrict__ tab,
                                                         const int* __restrict__ cap,
                                                         __hip_bfloat16* __restrict__ out) {
    int i = blockIdx.x * 256 + threadIdx.x;  // T*B*E total
    int e = i & (EE - 1);
    int tb = i >> 9;
    int t = tb >> 6;
    int b = tb & 63;
    int tok = cap[b * TT + t];
    out[i] = __float2bfloat16(tab[(size_t)tok * EE + e]);
}

// zero h step-0 buffer + barrier counters
__global__ __launch_bounds__(256) void init_kernel(__hip_bfloat16* __restrict__ hbuf,
                                                   int* __restrict__ bar) {
    int i = blockIdx.x * 256 + threadIdx.x;  // 3*64*512 threads
    hbuf[i] = __float2bfloat16(0.f);
    if (i < 64) bar[i] = 0;
}

// ---------------- gemm128: C[M,N] = A[M,K] @ B[N,K]^T (+bias) ----------------
// fp32 out (C) or bf16 out (Cb) if Cb != nullptr.

__global__ __launch_bounds__(256) void gemm128_kernel(
    const __hip_bfloat16* __restrict__ A,
    const __hip_bfloat16* __restrict__ Bm,
    const float* __restrict__ bias,
    float* __restrict__ C,
    __hip_bfloat16* __restrict__ Cb,
    int K, int N)
{
    __shared__ __align__(16) __hip_bfloat16 As[128 * 32];
    __shared__ __align__(16) __hip_bfloat16 Bs[128 * 32];

    int m0 = blockIdx.x * 128, n0 = blockIdx.y * 128;
    int tid = threadIdx.x;
    int wave = tid >> 6, lane = tid & 63;
    int wm = wave & 1, wn = wave >> 1;
    int row16 = lane & 15, quad = lane >> 4;

    int r0 = tid >> 2, cc = (tid & 3) * 8;
    int r1 = 64 + r0;
    const __hip_bfloat16* gA0 = A  + (size_t)(m0 + r0) * K + cc;
    const __hip_bfloat16* gA1 = A  + (size_t)(m0 + r1) * K + cc;
    const __hip_bfloat16* gB0 = Bm + (size_t)(n0 + r0) * K + cc;
    const __hip_bfloat16* gB1 = Bm + (size_t)(n0 + r1) * K + cc;
    __hip_bfloat16* lA0 = As + (size_t)(wave * 64) * 8;
    __hip_bfloat16* lA1 = As + (size_t)(256 + wave * 64) * 8;
    __hip_bfloat16* lB0 = Bs + (size_t)(wave * 64) * 8;
    __hip_bfloat16* lB1 = Bs + (size_t)(256 + wave * 64) * 8;

    const __hip_bfloat16* ra = As + (size_t)(wm * 64 + row16) * 32 + quad * 8;
    const __hip_bfloat16* rb = Bs + (size_t)(wn * 64 + row16) * 32 + quad * 8;

    f32x4 acc[4][4] = {};

    for (int k = 0; k < K; k += 32) {
        gload_lds16(gA0 + k, lA0);
        gload_lds16(gA1 + k, lA1);
        gload_lds16(gB0 + k, lB0);
        gload_lds16(gB1 + k, lB1);
        __syncthreads();
        bf16x8 af[4], bfr[4];
#pragma unroll
        for (int mt = 0; mt < 4; ++mt)
            af[mt] = *reinterpret_cast<const bf16x8*>(ra + mt * 16 * 32);
#pragma unroll
        for (int nt = 0; nt < 4; ++nt)
            bfr[nt] = *reinterpret_cast<const bf16x8*>(rb + nt * 16 * 32);
#pragma unroll
        for (int mt = 0; mt < 4; ++mt)
#pragma unroll
            for (int nt = 0; nt < 4; ++nt)
                acc[mt][nt] = __builtin_amdgcn_mfma_f32_16x16x32_bf16(af[mt], bfr[nt], acc[mt][nt], 0, 0, 0);
        __syncthreads();
    }

#pragma unroll
    for (int mt = 0; mt < 4; ++mt)
#pragma unroll
        for (int nt = 0; nt < 4; ++nt) {
            int col = n0 + wn * 64 + nt * 16 + row16;
            float bv = bias ? bias[col] : 0.f;
#pragma unroll
            for (int r = 0; r < 4; ++r) {
                int row = m0 + wm * 64 + mt * 16 + quad * 4 + r;
                size_t off = (size_t)row * N + col;
                float v = acc[mt][nt][r] + bv;
                if (Cb) Cb[off] = __float2bfloat16(v);
                else    C[off]  = v;
            }
        }
}

// ---------------- persistent recurrence kernel ----------------
// 32 blocks x 512 thr. Block owns 16-col slice of every 64x512 projection.
// KEY: h/q/ctx buffers ROTATE per timestep (no address reuse). Writes are
// sc0sc1 write-around; reads are PLAIN CACHED loads (safe: address never
// cached before its unique write). One acquire (buffer_inv) at kernel entry
// kills harness-poison stale lines; after that L2 is NEVER invalidated ->
// weights/GI0/KV(bf16) stay L2-resident all 20 steps. Barrier = relaxed-only
// monotonic counter. fp32 h carry lives in registers. 5 barriers/step.

__global__ __launch_bounds__(512) void recurrence_kernel(
    const float* __restrict__ GI0,            // [1280][1536] = xemb @ Wih0^T
    const __hip_bfloat16* __restrict__ wih,   // [3][1536][512]
    const __hip_bfloat16* __restrict__ whh,   // [3][1536][512]
    const float* __restrict__ bih,            // [3][1536]
    const float* __restrict__ bhh,
    const __hip_bfloat16* __restrict__ wq,    // [512][512] (in_proj rows 0..511)
    const float* __restrict__ bq,
    const __hip_bfloat16* __restrict__ wo,    // [512][512]
    const float* __restrict__ bo,
    const __hip_bfloat16* __restrict__ KVb,   // [4096][1024] bf16 (K | V)
    __hip_bfloat16* __restrict__ hbuf,        // [21][3][64][512] bf16 rotating
    float* __restrict__ qrot,                 // [20][64][512] fp32 rotating
    __hip_bfloat16* __restrict__ ctxrot,      // [20][64][512] bf16 rotating
    __hip_bfloat16* __restrict__ AO,          // [1280][512] (row = b*T + t)
    int* __restrict__ bar)
{
    __shared__ float smem[24 * 544];  // parts[24][32][17]; attn aliases low 4KB

    // one-time invalidate of this CU's L1 + XCD L2 (drop harness-poison lines)
    {
        int d = __hip_atomic_load(&bar[1], __ATOMIC_ACQUIRE, __HIP_MEMORY_SCOPE_AGENT);
        asm volatile("" :: "v"(d));
    }
    __syncthreads();

    const int tid = threadIdx.x;
    const int w = tid >> 6, lane = tid & 63;
    const int row16 = lane & 15, quad = lane >> 4;
    const int blk = blockIdx.x;
    const int c0 = blk * 16;
    const size_t HS = (size_t)64 * 512;

    f32x4 h0r = {0.f, 0.f, 0.f, 0.f}, h1r = h0r, h2r = h0r;

    int lgen = 0;
    auto gridbar = [&]() {
        asm volatile("s_waitcnt vmcnt(0)" ::: "memory");  // sc1 stores coherence-visible
        __syncthreads();
        if (tid == 0) {
            lgen++;
            __hip_atomic_fetch_add(&bar[0], 1, __ATOMIC_RELAXED, __HIP_MEMORY_SCOPE_AGENT);
            while (__hip_atomic_load(&bar[0], __ATOMIC_RELAXED, __HIP_MEMORY_SCOPE_AGENT) < NBLK * lgen)
                __builtin_amdgcn_s_sleep(1);
        }
        __syncthreads();
    };

#define PART(s, r, c) smem[(s) * 544 + (r) * 17 + (c)]

    auto gru_stage = [&](auto LC, int t) {
        constexpr int l = decltype(LC)::value;
        // state-in for step t = hbuf[t][l]; x for l>=1 = hbuf[t+1][l-1]; out = hbuf[t+1][l]
        const __hip_bfloat16* hown = hbuf + ((size_t)t * 3 + l) * HS;
        const __hip_bfloat16* xin  = l ? hbuf + ((size_t)(t + 1) * 3 + (l - 1)) * HS : hown;
        const __hip_bfloat16* Wihl = wih + (size_t)l * 1536 * 512;
        const __hip_bfloat16* Whhl = whh + (size_t)l * 1536 * 512;

        int src, rh, kseg, koff;
        constexpr int nk = l ? 8 : 4;
        if (l) { src = w >> 2; rh = (w >> 1) & 1; kseg = w & 1; koff = kseg * 256; }
        else   { src = 1;      rh = w >> 2;       kseg = w & 3; koff = kseg * 128; }

        // bulk PLAIN cached preload of A fragments (addresses fresh this step)
        const __hip_bfloat16* Asrc = src ? hown : xin;
        const __hip_bfloat16* pa = Asrc + (size_t)(rh * 32 + row16) * 512 + koff + quad * 8;
        bf16x8 af0[nk], af1[nk];
#pragma unroll
        for (int kk = 0; kk < nk; ++kk) {
            af0[kk] = *reinterpret_cast<const bf16x8*>(pa + kk * 32);
            af1[kk] = *reinterpret_cast<const bf16x8*>(pa + (size_t)16 * 512 + kk * 32);
        }

        const __hip_bfloat16* pw = (src ? Whhl : Wihl) + (size_t)(c0 + row16) * 512 + koff + quad * 8;
        f32x4 acc[3][2] = {};
#pragma unroll
        for (int kk = 0; kk < nk; ++kk) {
            int kb = kk * 32;
#pragma unroll
            for (int g = 0; g < 3; ++g) {
                bf16x8 wv = *reinterpret_cast<const bf16x8*>(pw + (size_t)g * 262144 + kb);
                acc[g][0] = __builtin_amdgcn_mfma_f32_16x16x32_bf16(af0[kk], wv, acc[g][0], 0, 0, 0);
                acc[g][1] = __builtin_amdgcn_mfma_f32_16x16x32_bf16(af1[kk], wv, acc[g][1], 0, 0, 0);
            }
        }
#pragma unroll
        for (int g = 0; g < 3; ++g) {
            int slot = l ? (g * 8 + src * 4 + rh * 2 + kseg) : (g * 8 + rh * 4 + kseg);
#pragma unroll
            for (int mf = 0; mf < 2; ++mf)
#pragma unroll
                for (int r = 0; r < 4; ++r)
                    PART(slot, mf * 16 + quad * 4 + r, row16) = (mf ? acc[g][1][r] : acc[g][0][r]);
        }
        __syncthreads();

        if (tid < 256) {
            int row = tid >> 2, cg = tid & 3;
            int rh2 = row >> 5, lr = row & 31;
            const float* bihl = bih + l * 1536;
            const float* bhhl = bhh + l * 1536;
            f32x4& hr = (l == 0) ? h0r : (l == 1) ? h1r : h2r;
            f32x4 gi4[3];
            if (!l) {
                const float* gp = GI0 + (size_t)(t * 64 + row) * 1536 + c0 + cg * 4;
#pragma unroll
                for (int g = 0; g < 3; ++g)
                    gi4[g] = *reinterpret_cast<const f32x4*>(gp + g * 512);
            }
            union { unsigned short us[4]; u64 u; } pk;
#pragma unroll
            for (int cc = 0; cc < 4; ++cc) {
                int col16 = cg * 4 + cc, col = c0 + col16;
                float gi[3], gh[3];
#pragma unroll
                for (int g = 0; g < 3; ++g) {
                    if (l) {
                        gi[g] = PART(g * 8 + rh2 * 2, lr, col16) + PART(g * 8 + rh2 * 2 + 1, lr, col16);
                        gh[g] = PART(g * 8 + 4 + rh2 * 2, lr, col16) + PART(g * 8 + 4 + rh2 * 2 + 1, lr, col16);
                    } else {
                        gh[g] = PART(g * 8 + rh2 * 4, lr, col16) + PART(g * 8 + rh2 * 4 + 1, lr, col16) +
                                PART(g * 8 + rh2 * 4 + 2, lr, col16) + PART(g * 8 + rh2 * 4 + 3, lr, col16);
                        gi[g] = gi4[g][cc];
                    }
                }
                float rr = sigmf(gi[0] + gh[0] + bihl[col] + bhhl[col]);
                float zz = sigmf(gi[1] + gh[1] + bihl[512 + col] + bhhl[512 + col]);
                float nn = tanhf(gi[2] + bihl[1024 + col] + rr * (gh[2] + bhhl[1024 + col]));
                float hnew = (1.f - zz) * nn + zz * hr[cc];
                hr[cc] = hnew;
                __hip_bfloat16 hv = __float2bfloat16(hnew);
                pk.us[cc] = *reinterpret_cast<unsigned short*>(&hv);
            }
            cstore8B(hbuf + ((size_t)(t + 1) * 3 + l) * HS + (size_t)row * 512 + c0 + cg * 4, pk.u);
        }
        __syncthreads();
    };

    // col-sliced 64x512 projection (K=512), A plain-cached bf16, W slice L2-hot.
    auto proj_stage = [&](const __hip_bfloat16* Asrc, const __hip_bfloat16* Wm,
                          const float* bias, bool to_q, int t) {
        int rh = w >> 2, kseg = w & 3, koff = kseg * 128;
        const __hip_bfloat16* pa = Asrc + (size_t)(rh * 32 + row16) * 512 + koff + quad * 8;
        bf16x8 af0[4], af1[4];
#pragma unroll
        for (int kk = 0; kk < 4; ++kk) {
            af0[kk] = *reinterpret_cast<const bf16x8*>(pa + kk * 32);
            af1[kk] = *reinterpret_cast<const bf16x8*>(pa + (size_t)16 * 512 + kk * 32);
        }
        const __hip_bfloat16* pw = Wm + (size_t)(c0 + row16) * 512 + koff + quad * 8;
        f32x4 a0 = {0.f, 0.f, 0.f, 0.f}, a1 = a0;
#pragma unroll
        for (int kk = 0; kk < 4; ++kk) {
            bf16x8 wv = *reinterpret_cast<const bf16x8*>(pw + kk * 32);
            a0 = __builtin_amdgcn_mfma_f32_16x16x32_bf16(af0[kk], wv, a0, 0, 0, 0);
            a1 = __builtin_amdgcn_mfma_f32_16x16x32_bf16(af1[kk], wv, a1, 0, 0, 0);
        }
#pragma unroll
        for (int r = 0; r < 4; ++r) {
            PART(w, quad * 4 + r, row16) = a0[r];
            PART(w, 16 + quad * 4 + r, row16) = a1[r];
        }
        __syncthreads();
        if (tid < 256) {
            int row = tid >> 2, cg = tid & 3;
            int rh2 = row >> 5, lr = row & 31;
            float v[4];
#pragma unroll
            for (int cc = 0; cc < 4; ++cc) {
                int col16 = cg * 4 + cc;
                float s = bias[c0 + col16];
#pragma unroll
                for (int ks = 0; ks < 4; ++ks) s += PART(rh2 * 4 + ks, lr, col16);
                v[cc] = s;
            }
            if (to_q) {
                float* dst = qrot + (size_t)t * HS + (size_t)row * 512 + c0 + cg * 4;
                union { float f[2]; u64 u; } p0, p1;
                p0.f[0] = v[0]; p0.f[1] = v[1];
                p1.f[0] = v[2]; p1.f[1] = v[3];
                cstore8B(dst, p0.u);
                cstore8B(dst + 2, p1.u);
            } else {
                union { unsigned short us[4]; u64 u; } pk;
#pragma unroll
                for (int cc = 0; cc < 4; ++cc) {
                    __hip_bfloat16 hv = __float2bfloat16(v[cc]);
                    pk.us[cc] = *reinterpret_cast<unsigned short*>(&hv);
                }
                cstore8B(AO + ((size_t)row * TT + t) * 512 + c0 + cg * 4, pk.u);
            }
        }
        __syncthreads();
    };

    // per-(b,head) softmax attention; block handles batches blk and blk+32
    auto attn_stage = [&](int t) {
        float* qls = smem;  // [2][512]
        const float* qsrc = qrot + (size_t)t * HS;
        if (tid < 256) {
            int rr = tid >> 7, off = (tid & 127) * 4;
            f32x4 v = *reinterpret_cast<const f32x4*>(qsrc + (size_t)(blk + rr * 32) * 512 + off);
            *reinterpret_cast<f32x4*>(qls + rr * 512 + off) = v;
        }
        __syncthreads();
#pragma unroll 1
        for (int rr = 0; rr < 2; ++rr) {
            int b = blk + rr * 32;
            const float* qh = qls + rr * 512 + w * 64;
            const __hip_bfloat16* kr = KVb + (size_t)(b * 64 + lane) * 1024 + w * 64;
            float sc = 0.f;
#pragma unroll
            for (int k8 = 0; k8 < 8; ++k8) {
                bf16x8 kv = *reinterpret_cast<const bf16x8*>(kr + k8 * 8);
                const float* qv = qh + k8 * 8;
#pragma unroll
                for (int e = 0; e < 8; ++e) sc += qv[e] * (float)kv[e];
            }
            sc *= 0.125f;  // 1/sqrt(64)
            float m = sc;
            for (int off = 32; off; off >>= 1) m = fmaxf(m, __shfl_xor(m, off, 64));
            float e = __expf(sc - m);
            float s = e;
            for (int off = 32; off; off >>= 1) s += __shfl_xor(s, off, 64);
            float p = e / s;
            const __hip_bfloat16* vb = KVb + (size_t)(b * 64) * 1024 + 512 + w * 64 + lane;
            float acc = 0.f;
#pragma unroll
            for (int si = 0; si < 64; ++si)
                acc += __shfl(p, si, 64) * (float)vb[(size_t)si * 1024];
            // pack lane pairs -> 4B sc1 store of 2 bf16
            float hi = __shfl_down(acc, 1, 64);
            if (!(lane & 1)) {
                __hip_bfloat16 e0 = __float2bfloat16(acc), e1 = __float2bfloat16(hi);
                unsigned pk = (unsigned)*reinterpret_cast<unsigned short*>(&e0) |
                              ((unsigned)*reinterpret_cast<unsigned short*>(&e1) << 16);
                cstore4B(ctxrot + (size_t)t * HS + (size_t)b * 512 + w * 64 + lane, pk);
            }
        }
        __syncthreads();
    };

#pragma unroll 1
    for (int t = 0; t < TT; ++t) {
        gru_stage(IC<0>{}, t); gridbar();
        gru_stage(IC<1>{}, t); gridbar();
        gru_stage(IC<2>{}, t); gridbar();
        proj_stage(hbuf + ((size_t)(t + 1) * 3 + 2) * HS, wq, bq, true, t); gridbar();
        attn_stage(t); gridbar();
        proj_stage(ctxrot + (size_t)t * HS, wo, bo, false, t);
        // no trailing barrier: step t+1 touches only t+1-indexed rotating buffers.
    }
#undef PART
}

// ---------------- host ----------------

extern "C" void kernel_launch(void* const* d_in, const int* in_sizes, int n_in,
                              void* d_out, int out_size, void* d_ws, size_t ws_size,
                              hipStream_t stream) {
    const float* enc        = (const float*)d_in[0];
    const int*   cap        = (const int*)d_in[1];
    const float* emb_tab    = (const float*)d_in[2];
    const float* w_ih       = (const float*)d_in[3];
    const float* w_hh       = (const float*)d_in[4];
    const float* b_ih       = (const float*)d_in[5];
    const float* b_hh       = (const float*)d_in[6];
    const float* in_proj_w  = (const float*)d_in[7];
    const float* in_proj_b  = (const float*)d_in[8];
    const float* out_proj_w = (const float*)d_in[9];
    const float* out_proj_b = (const float*)d_in[10];
    const float* fc_w       = (const float*)d_in[11];
    const float* fc_b       = (const float*)d_in[12];
    float* out = (float*)d_out;

    char* p = (char*)d_ws;
    auto alloc = [&](size_t bytes) {
        char* r = p;
        p += (bytes + 255) & ~(size_t)255;
        return r;
    };
    __hip_bfloat16* fcw_bf  = (__hip_bfloat16*)alloc((size_t)VV * HH * 2);
    __hip_bfloat16* enc_bf  = (__hip_bfloat16*)alloc((size_t)BB * 64 * HH * 2);
    __hip_bfloat16* inp_bf  = (__hip_bfloat16*)alloc((size_t)1536 * 512 * 2);
    __hip_bfloat16* wih_bf  = (__hip_bfloat16*)alloc((size_t)3 * 1536 * 512 * 2);
    __hip_bfloat16* whh_bf  = (__hip_bfloat16*)alloc((size_t)3 * 1536 * 512 * 2);
    __hip_bfloat16* wo_bf   = (__hip_bfloat16*)alloc((size_t)512 * 512 * 2);
    __hip_bfloat16* xemb_bf = (__hip_bfloat16*)alloc((size_t)TT * BB * EE * 2);
    __hip_bfloat16* KVb = (__hip_bfloat16*)alloc((size_t)4096 * 1024 * 2);
    float* GI0  = (float*)alloc((size_t)1280 * 1536 * 4);
    __hip_bfloat16* hbuf = (__hip_bfloat16*)alloc((size_t)(TT + 1) * 3 * 64 * 512 * 2);
    float* qrot = (float*)alloc((size_t)TT * 64 * 512 * 4);
    __hip_bfloat16* ctxrot = (__hip_bfloat16*)alloc((size_t)TT * 64 * 512 * 2);
    __hip_bfloat16* AO = (__hip_bfloat16*)alloc((size_t)1280 * 512 * 2);
    int* bar = (int*)alloc(256);

    auto cvt = [&](const float* src, __hip_bfloat16* dst, int n) {
        f2bf_kernel<<<(n + 255) / 256, 256, 0, stream>>>(src, dst, n);
    };
    cvt(fc_w, fcw_bf, VV * HH);
    cvt(enc, enc_bf, BB * 64 * HH);
    cvt(in_proj_w, inp_bf, 1536 * 512);
    cvt(w_ih, wih_bf, 3 * 1536 * 512);
    cvt(w_hh, whh_bf, 3 * 1536 * 512);
    cvt(out_proj_w, wo_bf, 512 * 512);
    gather_emb_kernel<<<(TT * BB * EE) / 256, 256, 0, stream>>>(emb_tab, cap, xemb_bf);
    init_kernel<<<(3 * 64 * 512) / 256, 256, 0, stream>>>(hbuf, bar);

    // KV = enc @ [Wk;Wv]^T + [bk;bv]   (4096 x 1024, K=512) -> bf16
    gemm128_kernel<<<dim3(32, 8), 256, 0, stream>>>(
        enc_bf, inp_bf + 512 * 512, in_proj_b + 512, nullptr, KVb, 512, 1024);

    // GI0 = xemb @ Wih0^T   (1280 x 1536, no bias) -> fp32
    gemm128_kernel<<<dim3(10, 12), 256, 0, stream>>>(
        xemb_bf, wih_bf, nullptr, GI0, nullptr, 512, 1536);

    // whole recurrence in one persistent kernel
    recurrence_kernel<<<NBLK, 512, 0, stream>>>(
        GI0, wih_bf, whh_bf, b_ih, b_hh,
        inp_bf, in_proj_b, wo_bf, out_proj_b,
        KVb, hbuf, qrot, ctxrot, AO, bar);

    // logits = AO @ fc_w^T + fc_b   (1280 x 32000) -> d_out (B,T,V)
    gemm128_kernel<<<dim3(10, 250), 256, 0, stream>>>(
        AO, fcw_bf, fc_b, out, nullptr, 512, VV);
}